// Round 1
// baseline (685.591 us; speedup 1.0000x reference)
//
#include <hip/hip_runtime.h>

using short8 = __attribute__((ext_vector_type(8))) short;
using f32x4  = __attribute__((ext_vector_type(4))) float;

__device__ inline unsigned short f2bf(float f) {
  unsigned u = __float_as_uint(f);
  u += 0x7fffu + ((u >> 16) & 1u);
  return (unsigned short)(u >> 16);
}

// ---------------- Kernel 0: weight transpose+cast ----------------
// wBt[o][k*256 + c] = bf16(conv_w[o][c][k]),  k = ky*3+kx
__global__ void prep_weights(const float* __restrict__ cw,
                             unsigned short* __restrict__ wBt) {
  int r = blockIdx.x * 256 + threadIdx.x;   // 0..2303 = k*256+c
  int o = blockIdx.y;                       // 0..255
  int k = r >> 8, c = r & 255;
  wBt[(size_t)o * 2304 + r] = f2bf(cw[(size_t)(o * 256 + c) * 9 + k]);
}

// ---------------- Kernel 1: offset conv, partial over C-chunks ----------------
// part[(b*8+chunk)][o(18)][h][w] = sum over 32 channels of 3x3 conv
__global__ __launch_bounds__(256, 4) void offset_partial(
    const float* __restrict__ x, const float* __restrict__ ow,
    float* __restrict__ part) {
  int bi = blockIdx.x;                 // 1024 blocks
  int b = bi >> 7, rem = bi & 127;
  int chunk = rem >> 4, hg = rem & 15;
  int h = (hg << 2) + (threadIdx.x >> 6);
  int w = threadIdx.x & 63;
  float acc[18];
#pragma unroll
  for (int o = 0; o < 18; ++o) acc[o] = 0.f;
  int c0 = chunk << 5;
  for (int ci = 0; ci < 32; ++ci) {
    int c = c0 + ci;
    const float* xp = x + ((size_t)((b << 8) + c) << 12);
    const float* wb = ow + c * 9;      // + o*2304 + ky*3+kx
#pragma unroll
    for (int ky = 0; ky < 3; ++ky) {
      int y = h + ky - 1;
      bool yv = (unsigned)y < 64u;
      const float* row = xp + (y << 6);
#pragma unroll
      for (int kx = 0; kx < 3; ++kx) {
        int xw = w + kx - 1;
        float v = (yv && (unsigned)xw < 64u) ? row[xw] : 0.f;
        const float* wp = wb + ky * 3 + kx;
#pragma unroll
        for (int o = 0; o < 18; ++o) acc[o] += v * wp[o * 2304];
      }
    }
  }
  float* dst = part + (((size_t)((b * 8 + chunk) * 18) << 12) + (h << 6) + w);
#pragma unroll
  for (int o = 0; o < 18; ++o) dst[(size_t)o << 12] = acc[o];
}

// ---------------- Kernel 1b: reduce partials + bias ----------------
__global__ void offset_reduce(const float* __restrict__ part,
                              const float* __restrict__ offb,
                              float* __restrict__ off_buf) {
  int idx = blockIdx.x * 256 + threadIdx.x;   // < 589824
  int p = idx & 4095;
  int t = idx >> 12;                          // (b*18+o)
  int b = t / 18, o = t - b * 18;
  float s = offb[o];
#pragma unroll
  for (int ch = 0; ch < 8; ++ch)
    s += part[(((size_t)((b * 8 + ch) * 18 + o)) << 12) + p];
  off_buf[idx] = s;
}

// ---------------- Kernel 2: fused sample + MFMA GEMM ----------------
// block = one (b, h) row: 64 px (M) x 256 outputs (N), K = 2304 (tap-major)
__global__ __launch_bounds__(256, 2) void deform_main(
    const float* __restrict__ x, const float* __restrict__ off,
    const unsigned short* __restrict__ wBt, float* __restrict__ out) {
  __shared__ float4 smem4[2752];               // 44032 B
  char* smem = (char*)smem4;
  float* cwf = (float*)smem;                   // [9*64] corner weights x4 (9216 B)
  int*   cif = (int*)(smem + 9216);            // [9*64] corner idx x4    (9216 B)
  unsigned short* At = (unsigned short*)(smem + 18432);  // [64][40] bf16 (5120 B)
  unsigned short* Bt = (unsigned short*)(smem + 23552);  // [256][40] bf16 (20480 B)

  int tid = threadIdx.x, lane = tid & 63, wave = tid >> 6;
  int b = blockIdx.x >> 6, h = blockIdx.x & 63;

  // --- coord/bilinear precompute for 9 taps x 64 px ---
  for (int it = tid; it < 576; it += 256) {
    int k = it >> 6, px = it & 63;
    int ky = k / 3, kx = k - ky * 3;
    float dy = off[((size_t)(b * 18 + 2 * k) << 12) + (h << 6) + px];
    float dx = off[((size_t)(b * 18 + 2 * k + 1) << 12) + (h << 6) + px];
    float py = (float)(h - 1 + ky) + dy;
    float pxx = (float)(px - 1 + kx) + dx;
    float y0f = floorf(py), x0f = floorf(pxx);
    int y0 = (int)y0f, x0 = (int)x0f;
    float wy1 = py - y0f, wx1 = pxx - x0f;
    float wy0 = 1.f - wy1, wx0 = 1.f - wx1;
    bool yv0 = (unsigned)y0 < 64u, yv1 = (unsigned)(y0 + 1) < 64u;
    bool xv0 = (unsigned)x0 < 64u, xv1 = (unsigned)(x0 + 1) < 64u;
    int yc0 = min(max(y0, 0), 63), yc1 = min(max(y0 + 1, 0), 63);
    int xc0 = min(max(x0, 0), 63), xc1 = min(max(x0 + 1, 0), 63);
    cwf[it * 4 + 0] = (yv0 && xv0) ? wy0 * wx0 : 0.f;
    cwf[it * 4 + 1] = (yv0 && xv1) ? wy0 * wx1 : 0.f;
    cwf[it * 4 + 2] = (yv1 && xv0) ? wy1 * wx0 : 0.f;
    cwf[it * 4 + 3] = (yv1 && xv1) ? wy1 * wx1 : 0.f;
    cif[it * 4 + 0] = (yc0 << 6) + xc0;
    cif[it * 4 + 1] = (yc0 << 6) + xc1;
    cif[it * 4 + 2] = (yc1 << 6) + xc0;
    cif[it * 4 + 3] = (yc1 << 6) + xc1;
  }
  __syncthreads();

  int m16 = lane & 15, quad = lane >> 4;
  int mtb = (wave & 1) * 2;        // M-tile base (2 tiles per wave)
  int ntb = (wave >> 1) * 8;       // N-tile base (8 tiles per wave)
  f32x4 acc[2][8];
#pragma unroll
  for (int i = 0; i < 2; ++i)
#pragma unroll
    for (int n = 0; n < 8; ++n) acc[i][n] = (f32x4){0.f, 0.f, 0.f, 0.f};

  for (int kt = 0; kt < 9; ++kt) {
    // per-lane (= per pixel) sampling constants for this tap
    float w0 = cwf[(kt * 64 + lane) * 4 + 0];
    float w1 = cwf[(kt * 64 + lane) * 4 + 1];
    float w2 = cwf[(kt * 64 + lane) * 4 + 2];
    float w3 = cwf[(kt * 64 + lane) * 4 + 3];
    int i0 = cif[(kt * 64 + lane) * 4 + 0];
    int i1 = cif[(kt * 64 + lane) * 4 + 1];
    int i2 = cif[(kt * 64 + lane) * 4 + 2];
    int i3 = cif[(kt * 64 + lane) * 4 + 3];
    for (int cc = 0; cc < 8; ++cc) {
      // ---- stage A: sample 8 channels per lane, write bf16 A-tile [px][kk] ----
      const float* xc = x + ((size_t)((b << 8) + (cc << 5) + wave * 8) << 12);
      short8 av;
#pragma unroll
      for (int i = 0; i < 8; ++i) {
        const float* p = xc + ((size_t)i << 12);
        float v = w0 * p[i0] + w1 * p[i1] + w2 * p[i2] + w3 * p[i3];
        av[i] = (short)f2bf(v);
      }
      *(short8*)(At + lane * 40 + wave * 8) = av;
      // ---- stage B: weight tile [o][kk] (64 B per o-row, L2-resident) ----
      int ks = kt * 8 + cc;
      const unsigned short* bs = wBt + (size_t)tid * 2304 + ks * 32;
#pragma unroll
      for (int j = 0; j < 4; ++j) {
        short8 bv = *(const short8*)(bs + j * 8);
        *(short8*)(Bt + tid * 40 + j * 8) = bv;
      }
      __syncthreads();
      // ---- MFMA: wave does 2 M-tiles x 8 N-tiles ----
      short8 a0 = *(const short8*)(At + (mtb * 16 + m16) * 40 + quad * 8);
      short8 a1 = *(const short8*)(At + ((mtb + 1) * 16 + m16) * 40 + quad * 8);
#pragma unroll
      for (int n = 0; n < 8; ++n) {
        short8 bf = *(const short8*)(Bt + ((ntb + n) * 16 + m16) * 40 + quad * 8);
        acc[0][n] = __builtin_amdgcn_mfma_f32_16x16x32_bf16(a0, bf, acc[0][n], 0, 0, 0);
        acc[1][n] = __builtin_amdgcn_mfma_f32_16x16x32_bf16(a1, bf, acc[1][n], 0, 0, 0);
      }
      __syncthreads();
    }
  }

  // ---- epilogue: transpose via LDS for coalesced stores, 2 chunks of 128 o ----
  float* ep = (float*)smem;   // [128][65]
  for (int half = 0; half < 2; ++half) {
    if ((wave >> 1) == half) {  // waves owning this o-half
#pragma unroll
      for (int mi = 0; mi < 2; ++mi)
#pragma unroll
        for (int n = 0; n < 8; ++n)
#pragma unroll
          for (int r = 0; r < 4; ++r) {
            int o_loc = n * 16 + m16;                 // 0..127 within half
            int px = (mtb + mi) * 16 + quad * 4 + r;  // D: row=m, col=n
            ep[o_loc * 65 + px] = acc[mi][n][r];
          }
    }
    __syncthreads();
#pragma unroll 4
    for (int j = 0; j < 32; ++j) {
      int idx = j * 256 + tid;
      int o = idx >> 6, px = idx & 63;
      out[(((size_t)((b << 8) + half * 128 + o)) << 12) + (h << 6) + px] =
          ep[o * 65 + px];
    }
    __syncthreads();
  }
}

extern "C" void kernel_launch(void* const* d_in, const int* in_sizes, int n_in,
                              void* d_out, int out_size, void* d_ws, size_t ws_size,
                              hipStream_t stream) {
  const float* x     = (const float*)d_in[0];
  const float* offw  = (const float*)d_in[1];
  const float* offb  = (const float*)d_in[2];
  const float* convw = (const float*)d_in[3];
  float* out = (float*)d_out;

  char* ws = (char*)d_ws;
  float* off_buf = (float*)ws;                              // 2,359,296 B
  float* part    = (float*)(ws + 2359296);                  // 18,874,368 B
  unsigned short* wBt = (unsigned short*)(ws + 2359296 + 18874368);  // 1,179,648 B

  prep_weights<<<dim3(9, 256), 256, 0, stream>>>(convw, wBt);
  offset_partial<<<1024, 256, 0, stream>>>(x, offw, part);
  offset_reduce<<<2304, 256, 0, stream>>>(part, offb, off_buf);
  deform_main<<<512, 256, 0, stream>>>(x, off_buf, wBt, out);
}

// Round 2
// 488.057 us; speedup vs baseline: 1.4047x; 1.4047x over previous
//
#include <hip/hip_runtime.h>

using short8 = __attribute__((ext_vector_type(8))) short;
using f32x4  = __attribute__((ext_vector_type(4))) float;

__device__ inline unsigned short f2bf(float f) {
  unsigned u = __float_as_uint(f);
  u += 0x7fffu + ((u >> 16) & 1u);
  return (unsigned short)(u >> 16);
}

// ---------------- Kernel 0: weight transpose+cast ----------------
// wBt[o][k*256 + c] = bf16(conv_w[o][c][k]),  k = ky*3+kx
__global__ void prep_weights(const float* __restrict__ cw,
                             unsigned short* __restrict__ wBt) {
  int r = blockIdx.x * 256 + threadIdx.x;   // 0..2303 = k*256+c
  int o = blockIdx.y;                       // 0..255
  int k = r >> 8, c = r & 255;
  wBt[(size_t)o * 2304 + r] = f2bf(cw[(size_t)(o * 256 + c) * 9 + k]);
}

// ---------------- Kernel 1: offset conv, partial over C-chunks ----------------
__global__ __launch_bounds__(256, 4) void offset_partial(
    const float* __restrict__ x, const float* __restrict__ ow,
    float* __restrict__ part) {
  int bi = blockIdx.x;                 // 1024 blocks
  int b = bi >> 7, rem = bi & 127;
  int chunk = rem >> 4, hg = rem & 15;
  int h = (hg << 2) + (threadIdx.x >> 6);
  int w = threadIdx.x & 63;
  float acc[18];
#pragma unroll
  for (int o = 0; o < 18; ++o) acc[o] = 0.f;
  int c0 = chunk << 5;
  for (int ci = 0; ci < 32; ++ci) {
    int c = c0 + ci;
    const float* xp = x + ((size_t)((b << 8) + c) << 12);
    const float* wb = ow + c * 9;      // + o*2304 + ky*3+kx
#pragma unroll
    for (int ky = 0; ky < 3; ++ky) {
      int y = h + ky - 1;
      bool yv = (unsigned)y < 64u;
      const float* row = xp + (y << 6);
#pragma unroll
      for (int kx = 0; kx < 3; ++kx) {
        int xw = w + kx - 1;
        float v = (yv && (unsigned)xw < 64u) ? row[xw] : 0.f;
        const float* wp = wb + ky * 3 + kx;
#pragma unroll
        for (int o = 0; o < 18; ++o) acc[o] += v * wp[o * 2304];
      }
    }
  }
  float* dst = part + (((size_t)((b * 8 + chunk) * 18) << 12) + (h << 6) + w);
#pragma unroll
  for (int o = 0; o < 18; ++o) dst[(size_t)o << 12] = acc[o];
}

// ---------------- Kernel 1b: reduce partials + bias ----------------
__global__ void offset_reduce(const float* __restrict__ part,
                              const float* __restrict__ offb,
                              float* __restrict__ off_buf) {
  int idx = blockIdx.x * 256 + threadIdx.x;   // < 589824
  int p = idx & 4095;
  int t = idx >> 12;                          // (b*18+o)
  int b = t / 18, o = t - b * 18;
  float s = offb[o];
#pragma unroll
  for (int ch = 0; ch < 8; ++ch)
    s += part[(((size_t)((b * 8 + ch) * 18 + o)) << 12) + p];
  off_buf[idx] = s;
}

// ---------------- Kernel 2: fused sample + MFMA GEMM ----------------
// block = one (b, h) row: 64 px (M) x 256 outputs (N), K = 2304
// Loop order: channel-chunk OUTER (L2 residency), tap INNER.
// XCD swizzle: b = blockIdx & 7 so each XCD owns one batch image.
__global__ __launch_bounds__(256, 3) void deform_main(
    const float* __restrict__ x, const float* __restrict__ off,
    const unsigned short* __restrict__ wBt, float* __restrict__ out) {
  __shared__ float4 smem4[2752];               // 44032 B
  char* smem = (char*)smem4;
  float* cwf = (float*)smem;                   // [9*64] corner weights x4 (9216 B)
  int*   cif = (int*)(smem + 9216);            // [9*64] corner idx x4    (9216 B)
  unsigned short* At = (unsigned short*)(smem + 18432);  // [64][40] bf16 (5120 B)
  unsigned short* Bt = (unsigned short*)(smem + 23552);  // [256][40] bf16 (20480 B)

  int tid = threadIdx.x, lane = tid & 63, wave = tid >> 6;
  int b = blockIdx.x & 7, h = blockIdx.x >> 3;

  // --- coord/bilinear precompute for 9 taps x 64 px ---
  for (int it = tid; it < 576; it += 256) {
    int k = it >> 6, px = it & 63;
    int ky = k / 3, kx = k - ky * 3;
    float dy = off[((size_t)(b * 18 + 2 * k) << 12) + (h << 6) + px];
    float dx = off[((size_t)(b * 18 + 2 * k + 1) << 12) + (h << 6) + px];
    float py = (float)(h - 1 + ky) + dy;
    float pxx = (float)(px - 1 + kx) + dx;
    float y0f = floorf(py), x0f = floorf(pxx);
    int y0 = (int)y0f, x0 = (int)x0f;
    float wy1 = py - y0f, wx1 = pxx - x0f;
    float wy0 = 1.f - wy1, wx0 = 1.f - wx1;
    bool yv0 = (unsigned)y0 < 64u, yv1 = (unsigned)(y0 + 1) < 64u;
    bool xv0 = (unsigned)x0 < 64u, xv1 = (unsigned)(x0 + 1) < 64u;
    int yc0 = min(max(y0, 0), 63), yc1 = min(max(y0 + 1, 0), 63);
    int xc0 = min(max(x0, 0), 63), xc1 = min(max(x0 + 1, 0), 63);
    cwf[it * 4 + 0] = (yv0 && xv0) ? wy0 * wx0 : 0.f;
    cwf[it * 4 + 1] = (yv0 && xv1) ? wy0 * wx1 : 0.f;
    cwf[it * 4 + 2] = (yv1 && xv0) ? wy1 * wx0 : 0.f;
    cwf[it * 4 + 3] = (yv1 && xv1) ? wy1 * wx1 : 0.f;
    cif[it * 4 + 0] = (yc0 << 6) + xc0;
    cif[it * 4 + 1] = (yc0 << 6) + xc1;
    cif[it * 4 + 2] = (yc1 << 6) + xc0;
    cif[it * 4 + 3] = (yc1 << 6) + xc1;
  }
  __syncthreads();

  int m16 = lane & 15, quad = lane >> 4;
  f32x4 acc[4][4];   // wave covers all 4 M-tiles x 4 N-tiles (n = wave*4+j)
#pragma unroll
  for (int i = 0; i < 4; ++i)
#pragma unroll
    for (int j = 0; j < 4; ++j) acc[i][j] = (f32x4){0.f, 0.f, 0.f, 0.f};

  for (int cc = 0; cc < 8; ++cc) {        // 32-channel chunks: OUTER
    for (int kt = 0; kt < 9; ++kt) {      // taps: INNER (x chunk stays L2-hot)
      // per-lane (= per pixel) sampling constants for this tap
      float4 wv = *(const float4*)(cwf + (kt * 64 + lane) * 4);
      int4   iv = *(const int4*)(cif + (kt * 64 + lane) * 4);
      // ---- stage A: sample 8 channels per lane, write bf16 A-tile [px][kk] ----
      const float* xc = x + ((size_t)((b << 8) + (cc << 5) + wave * 8) << 12);
      short8 av;
#pragma unroll
      for (int i = 0; i < 8; ++i) {
        const float* p = xc + ((size_t)i << 12);
        float v = wv.x * p[iv.x] + wv.y * p[iv.y] + wv.z * p[iv.z] + wv.w * p[iv.w];
        av[i] = (short)f2bf(v);
      }
      // ---- stage B: weight tile [o][kk] (64 B per o-row, L2-resident) ----
      int ks = kt * 8 + cc;
      const unsigned short* bs = wBt + (size_t)tid * 2304 + ks * 32;
      short8 bv0 = *(const short8*)(bs);
      short8 bv1 = *(const short8*)(bs + 8);
      short8 bv2 = *(const short8*)(bs + 16);
      short8 bv3 = *(const short8*)(bs + 24);
      *(short8*)(At + lane * 40 + wave * 8) = av;
      *(short8*)(Bt + tid * 40 + 0)  = bv0;
      *(short8*)(Bt + tid * 40 + 8)  = bv1;
      *(short8*)(Bt + tid * 40 + 16) = bv2;
      *(short8*)(Bt + tid * 40 + 24) = bv3;
      __syncthreads();
      // ---- MFMA: wave does 4 M-tiles x 4 N-tiles (n = wave*4+j) ----
      short8 af[4], bf[4];
#pragma unroll
      for (int mt = 0; mt < 4; ++mt)
        af[mt] = *(const short8*)(At + (mt * 16 + m16) * 40 + quad * 8);
#pragma unroll
      for (int j = 0; j < 4; ++j)
        bf[j] = *(const short8*)(Bt + ((wave * 4 + j) * 16 + m16) * 40 + quad * 8);
#pragma unroll
      for (int mt = 0; mt < 4; ++mt)
#pragma unroll
        for (int j = 0; j < 4; ++j)
          acc[mt][j] = __builtin_amdgcn_mfma_f32_16x16x32_bf16(af[mt], bf[j], acc[mt][j], 0, 0, 0);
      __syncthreads();
    }
  }

  // ---- epilogue: transpose via LDS for coalesced stores, 2 halves of 128 o ----
  // n = wave*4+j -> o = wave*64 + j*16 + m16 ; px = mt*16 + quad*4 + r
  float* ep = (float*)smem;   // [128][65]
  for (int half = 0; half < 2; ++half) {
    if ((wave >> 1) == half) {
#pragma unroll
      for (int mt = 0; mt < 4; ++mt)
#pragma unroll
        for (int j = 0; j < 4; ++j)
#pragma unroll
          for (int r = 0; r < 4; ++r) {
            int o_loc = (wave & 1) * 64 + j * 16 + m16;   // 0..127 within half
            int px = mt * 16 + quad * 4 + r;
            ep[o_loc * 65 + px] = acc[mt][j][r];
          }
    }
    __syncthreads();
#pragma unroll 4
    for (int t = 0; t < 32; ++t) {
      int idx = t * 256 + tid;
      int o = idx >> 6, px = idx & 63;
      out[(((size_t)((b << 8) + half * 128 + o)) << 12) + (h << 6) + px] =
          ep[o * 65 + px];
    }
    __syncthreads();
  }
}

extern "C" void kernel_launch(void* const* d_in, const int* in_sizes, int n_in,
                              void* d_out, int out_size, void* d_ws, size_t ws_size,
                              hipStream_t stream) {
  const float* x     = (const float*)d_in[0];
  const float* offw  = (const float*)d_in[1];
  const float* offb  = (const float*)d_in[2];
  const float* convw = (const float*)d_in[3];
  float* out = (float*)d_out;

  char* ws = (char*)d_ws;
  float* off_buf = (float*)ws;                              // 2,359,296 B
  float* part    = (float*)(ws + 2359296);                  // 18,874,368 B
  unsigned short* wBt = (unsigned short*)(ws + 2359296 + 18874368);  // 1,179,648 B

  prep_weights<<<dim3(9, 256), 256, 0, stream>>>(convw, wBt);
  offset_partial<<<1024, 256, 0, stream>>>(x, offw, part);
  offset_reduce<<<2304, 256, 0, stream>>>(part, offb, off_buf);
  deform_main<<<512, 256, 0, stream>>>(x, off_buf, wBt, out);
}

// Round 3
// 409.595 us; speedup vs baseline: 1.6738x; 1.1916x over previous
//
#include <hip/hip_runtime.h>

using short8 = __attribute__((ext_vector_type(8))) short;
using f32x4  = __attribute__((ext_vector_type(4))) float;

__device__ inline unsigned short f2bf(float f) {
  unsigned u = __float_as_uint(f);
  u += 0x7fffu + ((u >> 16) & 1u);
  return (unsigned short)(u >> 16);
}

// 8-byte load with only 4-byte alignment guaranteed (x0 can be odd).
// memcpy lets the compiler pick dwordx2 if unaligned VMEM is allowed,
// else it splits into two dwords — correct either way.
__device__ inline float2 ld_f2(const float* p) {
  float2 v;
  __builtin_memcpy(&v, p, sizeof(float2));
  return v;
}

// barrier that waits LDS only — global loads stay outstanding (pipeline!)
__device__ inline void barrier_lgkm() {
  asm volatile("s_waitcnt lgkmcnt(0)\n\ts_barrier" ::: "memory");
}

// ---------------- Kernel 0: weight transpose+cast ----------------
// wBt[o][k*256 + c... ] layout: wBt[o][tap*256 + c] bf16
__global__ void prep_weights(const float* __restrict__ cw,
                             unsigned short* __restrict__ wBt) {
  int r = blockIdx.x * 256 + threadIdx.x;   // 0..2303 = k*256+c
  int o = blockIdx.y;                       // 0..255
  int k = r >> 8, c = r & 255;
  wBt[(size_t)o * 2304 + r] = f2bf(cw[(size_t)(o * 256 + c) * 9 + k]);
}

// ---------------- Kernel 1: offset conv, partial over C-chunks ----------------
__global__ __launch_bounds__(256, 4) void offset_partial(
    const float* __restrict__ x, const float* __restrict__ ow,
    float* __restrict__ part) {
  int bi = blockIdx.x;                 // 1024 blocks
  int b = bi >> 7, rem = bi & 127;
  int chunk = rem >> 4, hg = rem & 15;
  int h = (hg << 2) + (threadIdx.x >> 6);
  int w = threadIdx.x & 63;
  float acc[18];
#pragma unroll
  for (int o = 0; o < 18; ++o) acc[o] = 0.f;
  int c0 = chunk << 5;
  for (int ci = 0; ci < 32; ++ci) {
    int c = c0 + ci;
    const float* xp = x + ((size_t)((b << 8) + c) << 12);
    const float* wb = ow + c * 9;
#pragma unroll
    for (int ky = 0; ky < 3; ++ky) {
      int y = h + ky - 1;
      bool yv = (unsigned)y < 64u;
      const float* row = xp + (y << 6);
#pragma unroll
      for (int kx = 0; kx < 3; ++kx) {
        int xw = w + kx - 1;
        float v = (yv && (unsigned)xw < 64u) ? row[xw] : 0.f;
        const float* wp = wb + ky * 3 + kx;
#pragma unroll
        for (int o = 0; o < 18; ++o) acc[o] += v * wp[o * 2304];
      }
    }
  }
  float* dst = part + (((size_t)((b * 8 + chunk) * 18) << 12) + (h << 6) + w);
#pragma unroll
  for (int o = 0; o < 18; ++o) dst[(size_t)o << 12] = acc[o];
}

// ---------------- Kernel 1b: reduce partials + bias ----------------
__global__ void offset_reduce(const float* __restrict__ part,
                              const float* __restrict__ offb,
                              float* __restrict__ off_buf) {
  int idx = blockIdx.x * 256 + threadIdx.x;   // < 589824
  int p = idx & 4095;
  int t = idx >> 12;                          // (b*18+o)
  int b = t / 18, o = t - b * 18;
  float s = offb[o];
#pragma unroll
  for (int ch = 0; ch < 8; ++ch)
    s += part[(((size_t)((b * 8 + ch) * 18 + o)) << 12) + p];
  off_buf[idx] = s;
}

// ---------------- helpers for the main kernel ----------------
__device__ inline void gather8(const float* __restrict__ x, int b, int wave,
                               int lane, int jt, const int2* cif2,
                               const float4* cwf4, float2 (*g)[2], float4& wq) {
  int cc = jt / 9, kt = jt - cc * 9;
  int2 rb = cif2[kt * 64 + lane];
  wq = cwf4[kt * 64 + lane];
  const float* base = x + ((size_t)((b << 8) + cc * 32 + wave * 8) << 12);
#pragma unroll
  for (int i = 0; i < 8; ++i) {
    const float* pc = base + ((size_t)i << 12);
    g[i][0] = ld_f2(pc + rb.x);
    g[i][1] = ld_f2(pc + rb.y);
  }
}

__device__ inline void loadB(const unsigned short* __restrict__ wBt, int wave,
                             int m16, int quad, int jt, short8* bf) {
  int cc = jt / 9, kt = jt - cc * 9;
  int ks = kt * 8 + cc;
  const unsigned short* bp =
      wBt + (size_t)(wave * 64 + m16) * 2304 + ks * 32 + quad * 8;
#pragma unroll
  for (int j = 0; j < 4; ++j)
    bf[j] = *(const short8*)(bp + (size_t)j * 36864);   // +16 o rows
}

// ---------------- Kernel 2: fused sample + MFMA GEMM ----------------
// block = one (b,h) row: 64 px (M) x 256 outputs (N), K = 2304
// cc outer / tap inner (L2-resident x chunk); XCD swizzle b = blk&7.
// Pipelined: gathers+B-frags for it+1 issued before an lgkm-only barrier,
// in flight across MFMA of it. At double-buffered, one barrier per iter.
__global__ __launch_bounds__(256, 2) void deform_main(
    const float* __restrict__ x, const float* __restrict__ off,
    const unsigned short* __restrict__ wBt, float* __restrict__ out) {
  __shared__ float4 smem4[2080];               // 33280 B
  char* smem = (char*)smem4;
  float4* cwf4 = (float4*)smem;                          // 576*16 = 9216 B
  int2*   cif2 = (int2*)(smem + 9216);                   // 576*8  = 4608 B
  unsigned short* At = (unsigned short*)(smem + 13824);  // 2 x [64][40] bf16

  int tid = threadIdx.x, lane = tid & 63, wave = tid >> 6;
  int b = blockIdx.x & 7, h = blockIdx.x >> 3;

  // --- coord/bilinear precompute: x-corners fused into pair loads ---
  for (int it = tid; it < 576; it += 256) {
    int k = it >> 6, px = it & 63;
    int ky = k / 3, kx = k - ky * 3;
    float dy = off[((size_t)(b * 18 + 2 * k) << 12) + (h << 6) + px];
    float dx = off[((size_t)(b * 18 + 2 * k + 1) << 12) + (h << 6) + px];
    float py = (float)(h - 1 + ky) + dy;
    float pxx = (float)(px - 1 + kx) + dx;
    float y0f = floorf(py), x0f = floorf(pxx);
    int y0 = (int)y0f, x0 = (int)x0f;
    float wy1 = py - y0f, wx1 = pxx - x0f;
    // x: one pair [xb, xb+1] with left/right weights (validity folded in)
    int xb; float wxl, wxr;
    if (x0 >= 0 && x0 <= 62)      { xb = x0; wxl = 1.f - wx1; wxr = wx1; }
    else if (x0 == -1)            { xb = 0;  wxl = wx1;       wxr = 0.f; }
    else if (x0 == 63)            { xb = 62; wxl = 0.f;       wxr = 1.f - wx1; }
    else                          { xb = 0;  wxl = 0.f;       wxr = 0.f; }
    // y: two rows with validity-masked weights
    float wy0v = ((unsigned)y0 < 64u) ? (1.f - wy1) : 0.f;
    float wy1v = ((unsigned)(y0 + 1) < 64u) ? wy1 : 0.f;
    int yc0 = min(max(y0, 0), 63), yc1 = min(max(y0 + 1, 0), 63);
    cwf4[it] = make_float4(wy0v * wxl, wy0v * wxr, wy1v * wxl, wy1v * wxr);
    cif2[it] = make_int2((yc0 << 6) + xb, (yc1 << 6) + xb);
  }
  __syncthreads();

  int m16 = lane & 15, quad = lane >> 4;
  f32x4 acc[4][4];
#pragma unroll
  for (int i = 0; i < 4; ++i)
#pragma unroll
    for (int j = 0; j < 4; ++j) acc[i][j] = (f32x4){0.f, 0.f, 0.f, 0.f};

  // prologue: prefetch iteration 0
  float2 g[8][2]; float4 wq; short8 bcur[4];
  gather8(x, b, wave, lane, 0, cif2, cwf4, g, wq);
  loadB(wBt, wave, m16, quad, 0, bcur);

  for (int it = 0; it < 72; ++it) {
    int buf = it & 1;
    // ---- convert + write A-tile (waits vmcnt for g automatically) ----
    short8 av;
#pragma unroll
    for (int i = 0; i < 8; ++i) {
      float v = wq.x * g[i][0].x + wq.y * g[i][0].y +
                wq.z * g[i][1].x + wq.w * g[i][1].y;
      av[i] = (short)f2bf(v);
    }
    *(short8*)(At + buf * 2560 + lane * 40 + wave * 8) = av;
    // ---- prefetch it+1 (B first, then gathers) — stays in flight ----
    int jn = (it < 71) ? it + 1 : 71;
    short8 bnext[4]; float2 gn[8][2]; float4 wqn;
    loadB(wBt, wave, m16, quad, jn, bnext);
    gather8(x, b, wave, lane, jn, cif2, cwf4, gn, wqn);
    // ---- LDS-only barrier: outstanding global loads NOT drained ----
    barrier_lgkm();
    // ---- fragments + MFMA ----
    short8 af[4];
#pragma unroll
    for (int mt = 0; mt < 4; ++mt)
      af[mt] = *(const short8*)(At + buf * 2560 + (mt * 16 + m16) * 40 + quad * 8);
#pragma unroll
    for (int mt = 0; mt < 4; ++mt)
#pragma unroll
      for (int j = 0; j < 4; ++j)
        acc[mt][j] = __builtin_amdgcn_mfma_f32_16x16x32_bf16(af[mt], bcur[j],
                                                             acc[mt][j], 0, 0, 0);
    // rotate pipeline registers
#pragma unroll
    for (int i = 0; i < 8; ++i) { g[i][0] = gn[i][0]; g[i][1] = gn[i][1]; }
    wq = wqn;
#pragma unroll
    for (int j = 0; j < 4; ++j) bcur[j] = bnext[j];
  }
  __syncthreads();   // full drain before smem reuse

  // ---- epilogue: transpose via LDS for coalesced stores ----
  // n = wave*4+j -> o = wave*64 + j*16 + m16 ; px = mt*16 + quad*4 + r
  float* ep = (float*)smem;   // [128][65] floats = 33280 B
  for (int half = 0; half < 2; ++half) {
    if ((wave >> 1) == half) {
#pragma unroll
      for (int mt = 0; mt < 4; ++mt)
#pragma unroll
        for (int j = 0; j < 4; ++j)
#pragma unroll
          for (int r = 0; r < 4; ++r) {
            int o_loc = (wave & 1) * 64 + j * 16 + m16;
            int px = mt * 16 + quad * 4 + r;
            ep[o_loc * 65 + px] = acc[mt][j][r];
          }
    }
    __syncthreads();
#pragma unroll 4
    for (int t = 0; t < 32; ++t) {
      int idx = t * 256 + tid;
      int o = idx >> 6, px = idx & 63;
      out[(((size_t)((b << 8) + half * 128 + o)) << 12) + (h << 6) + px] =
          ep[o * 65 + px];
    }
    __syncthreads();
  }
}

extern "C" void kernel_launch(void* const* d_in, const int* in_sizes, int n_in,
                              void* d_out, int out_size, void* d_ws, size_t ws_size,
                              hipStream_t stream) {
  const float* x     = (const float*)d_in[0];
  const float* offw  = (const float*)d_in[1];
  const float* offb  = (const float*)d_in[2];
  const float* convw = (const float*)d_in[3];
  float* out = (float*)d_out;

  char* ws = (char*)d_ws;
  float* off_buf = (float*)ws;                              // 2,359,296 B
  float* part    = (float*)(ws + 2359296);                  // 18,874,368 B
  unsigned short* wBt = (unsigned short*)(ws + 2359296 + 18874368);  // 1,179,648 B

  prep_weights<<<dim3(9, 256), 256, 0, stream>>>(convw, wBt);
  offset_partial<<<1024, 256, 0, stream>>>(x, offw, part);
  offset_reduce<<<2304, 256, 0, stream>>>(part, offb, off_buf);
  deform_main<<<512, 256, 0, stream>>>(x, off_buf, wBt, out);
}

// Round 4
// 268.138 us; speedup vs baseline: 2.5569x; 1.5276x over previous
//
#include <hip/hip_runtime.h>

using short8 = __attribute__((ext_vector_type(8))) short;
using f32x4  = __attribute__((ext_vector_type(4))) float;

__device__ inline unsigned short f2bf(float f) {
  unsigned u = __float_as_uint(f);
  u += 0x7fffu + ((u >> 16) & 1u);
  return (unsigned short)(u >> 16);
}
__device__ inline float bf2f(short s) {
  return __uint_as_float(((unsigned)(unsigned short)s) << 16);
}

// barrier that waits LDS only — global loads stay outstanding (pipeline!)
__device__ inline void barrier_lgkm() {
  asm volatile("s_waitcnt lgkmcnt(0)\n\ts_barrier" ::: "memory");
}

// ---------------- Kernel 0a: x NCHW fp32 -> xT[b][y*64+x][c] bf16 ----------------
__global__ __launch_bounds__(256) void prep_xT(const float* __restrict__ x,
                                               unsigned short* __restrict__ xT) {
  __shared__ unsigned short tile[64 * 260];   // [x][c], stride 260 (33280 B)
  int b = blockIdx.x >> 6, y = blockIdx.x & 63;
  int xc = threadIdx.x & 63, cq = threadIdx.x >> 6;
#pragma unroll 4
  for (int i = 0; i < 64; ++i) {
    int c = i * 4 + cq;
    float v = x[((size_t)((b << 8) + c) << 12) + (y << 6) + xc];
    tile[xc * 260 + c] = f2bf(v);
  }
  __syncthreads();
  int tid = threadIdx.x;
#pragma unroll 4
  for (int i = 0; i < 16; ++i) {
    int u = i * 256 + tid;            // 4096 units of 4 ch
    int site = u >> 6, c4 = u & 63;   // site = x (row y fixed)
    ushort4 val = *(const ushort4*)(tile + site * 260 + c4 * 4);
    *(ushort4*)(xT + ((size_t)((b << 12) + (y << 6) + site) << 8) + c4 * 4) = val;
  }
}

// ---------------- Kernel 0b: weights -> wBt2[ks][o][kc] bf16 ----------------
// ks = kt*8+cc (kt = ks>>3, cc = ks&7), kc = c - cc*32
__global__ void prep_weights(const float* __restrict__ cw,
                             unsigned short* __restrict__ wBt2) {
  int e = blockIdx.x * 256 + threadIdx.x;   // < 589824
  int kc = e & 31, o = (e >> 5) & 255, ks = e >> 13;
  int c = (ks & 7) * 32 + kc, kt = ks >> 3;
  wBt2[e] = f2bf(cw[(size_t)(o * 256 + c) * 9 + kt]);
}

// ---------------- Kernel 1: offset conv, partial over C-chunks ----------------
__global__ __launch_bounds__(256, 4) void offset_partial(
    const float* __restrict__ x, const float* __restrict__ ow,
    float* __restrict__ part) {
  int bi = blockIdx.x;                 // 1024 blocks
  int b = bi >> 7, rem = bi & 127;
  int chunk = rem >> 4, hg = rem & 15;
  int h = (hg << 2) + (threadIdx.x >> 6);
  int w = threadIdx.x & 63;
  float acc[18];
#pragma unroll
  for (int o = 0; o < 18; ++o) acc[o] = 0.f;
  int c0 = chunk << 5;
  for (int ci = 0; ci < 32; ++ci) {
    int c = c0 + ci;
    const float* xp = x + ((size_t)((b << 8) + c) << 12);
    const float* wb = ow + c * 9;
#pragma unroll
    for (int ky = 0; ky < 3; ++ky) {
      int y = h + ky - 1;
      bool yv = (unsigned)y < 64u;
      const float* row = xp + (y << 6);
#pragma unroll
      for (int kx = 0; kx < 3; ++kx) {
        int xw = w + kx - 1;
        float v = (yv && (unsigned)xw < 64u) ? row[xw] : 0.f;
        const float* wp = wb + ky * 3 + kx;
#pragma unroll
        for (int o = 0; o < 18; ++o) acc[o] += v * wp[o * 2304];
      }
    }
  }
  float* dst = part + (((size_t)((b * 8 + chunk) * 18) << 12) + (h << 6) + w);
#pragma unroll
  for (int o = 0; o < 18; ++o) dst[(size_t)o << 12] = acc[o];
}

// ---------------- Kernel 1b: reduce partials + bias ----------------
__global__ void offset_reduce(const float* __restrict__ part,
                              const float* __restrict__ offb,
                              float* __restrict__ off_buf) {
  int idx = blockIdx.x * 256 + threadIdx.x;   // < 589824
  int p = idx & 4095;
  int t = idx >> 12;                          // (b*18+o)
  int b = t / 18, o = t - b * 18;
  float s = offb[o];
#pragma unroll
  for (int ch = 0; ch < 8; ++ch)
    s += part[(((size_t)((b * 8 + ch) * 18 + o)) << 12) + p];
  off_buf[idx] = s;
}

// ---------------- helpers for the main kernel ----------------
// Quad-contiguous gather: quad (4 lanes) <-> one (px, corner) 64-B channel run.
__device__ inline void gather4(const unsigned short* __restrict__ xT,
                               int bbase, int q, int jt,
                               const int2* cif2, const float4* cwf4,
                               int px, short8* g, float4& wq) {
  int cc = jt / 9, kt = jt - cc * 9;
  int2 si = cif2[kt * 64 + px];
  wq = cwf4[kt * 64 + px];
  const unsigned short* base = xT + (size_t)(unsigned)(bbase + cc * 32 + q * 8);
  g[0] = *(const short8*)(base + si.x);
  g[1] = *(const short8*)(base + si.x + 256);
  g[2] = *(const short8*)(base + si.y);
  g[3] = *(const short8*)(base + si.y + 256);
}

// Contiguous B-frag loads: wave reads 1 KB contiguous per frag.
__device__ inline void loadB(const unsigned short* __restrict__ wBt2, int wave,
                             int m16, int quad, int jt, short8* bf) {
  int cc = jt / 9, kt = jt - cc * 9;
  int ks = kt * 8 + cc;
  const unsigned short* bp =
      wBt2 + ((size_t)ks << 13) + (wave << 11) + m16 * 32 + quad * 8;
#pragma unroll
  for (int j = 0; j < 4; ++j)
    bf[j] = *(const short8*)(bp + j * 512);
}

// ---------------- Kernel 2: fused sample + MFMA GEMM ----------------
// block = one (b,h) row: 64 px (M) x 256 outputs (N), K = 2304
// NHWC-bf16 source; all VMEM 16 B/lane, quad-contiguous. cc outer (L2).
__global__ __launch_bounds__(256, 2) void deform_main(
    const unsigned short* __restrict__ xT, const float* __restrict__ off,
    const unsigned short* __restrict__ wBt2, float* __restrict__ out) {
  __shared__ float4 smem4[2080];               // 33280 B
  char* smem = (char*)smem4;
  float4* cwf4 = (float4*)smem;                          // 576*16 = 9216 B
  int2*   cif2 = (int2*)(smem + 9216);                   // 576*8  = 4608 B
  unsigned short* At = (unsigned short*)(smem + 13824);  // 2 x [64][40] bf16

  int tid = threadIdx.x, lane = tid & 63, wave = tid >> 6;
  int b = blockIdx.x & 7, h = blockIdx.x >> 3;

  // --- coord/bilinear precompute (sites scaled by 256 = channel stride) ---
  for (int it = tid; it < 576; it += 256) {
    int k = it >> 6, px = it & 63;
    int ky = k / 3, kx = k - ky * 3;
    float dy = off[((size_t)(b * 18 + 2 * k) << 12) + (h << 6) + px];
    float dx = off[((size_t)(b * 18 + 2 * k + 1) << 12) + (h << 6) + px];
    float py = (float)(h - 1 + ky) + dy;
    float pxx = (float)(px - 1 + kx) + dx;
    float y0f = floorf(py), x0f = floorf(pxx);
    int y0 = (int)y0f, x0 = (int)x0f;
    float wy1 = py - y0f, wx1 = pxx - x0f;
    int xb; float wxl, wxr;
    if (x0 >= 0 && x0 <= 62)      { xb = x0; wxl = 1.f - wx1; wxr = wx1; }
    else if (x0 == -1)            { xb = 0;  wxl = wx1;       wxr = 0.f; }
    else if (x0 == 63)            { xb = 62; wxl = 0.f;       wxr = 1.f - wx1; }
    else                          { xb = 0;  wxl = 0.f;       wxr = 0.f; }
    float wy0v = ((unsigned)y0 < 64u) ? (1.f - wy1) : 0.f;
    float wy1v = ((unsigned)(y0 + 1) < 64u) ? wy1 : 0.f;
    int yc0 = min(max(y0, 0), 63), yc1 = min(max(y0 + 1, 0), 63);
    cwf4[it] = make_float4(wy0v * wxl, wy0v * wxr, wy1v * wxl, wy1v * wxr);
    cif2[it] = make_int2(((yc0 << 6) + xb) << 8, ((yc1 << 6) + xb) << 8);
  }
  __syncthreads();

  int m16 = lane & 15, quad = lane >> 4;
  int px = wave * 16 + (lane >> 2);   // gather mapping: quad <-> (px,corner) run
  int q  = lane & 3;                  // 8-ch slice within the 32-ch run
  int bbase = b << 20;
  f32x4 acc[4][4];
#pragma unroll
  for (int i = 0; i < 4; ++i)
#pragma unroll
    for (int j = 0; j < 4; ++j) acc[i][j] = (f32x4){0.f, 0.f, 0.f, 0.f};

  // prologue: prefetch iteration 0
  short8 g[4]; float4 wq; short8 bcur[4];
  gather4(xT, bbase, q, 0, cif2, cwf4, px, g, wq);
  loadB(wBt2, wave, m16, quad, 0, bcur);

  for (int it = 0; it < 72; ++it) {
    int buf = it & 1;
    // ---- bilinear combine + write A-tile (vmcnt waits on g use) ----
    short8 av;
#pragma unroll
    for (int i = 0; i < 8; ++i) {
      float v = wq.x * bf2f(g[0][i]) + wq.y * bf2f(g[1][i]) +
                wq.z * bf2f(g[2][i]) + wq.w * bf2f(g[3][i]);
      av[i] = (short)f2bf(v);
    }
    *(short8*)(At + buf * 2560 + px * 40 + q * 8) = av;
    // ---- prefetch it+1 — stays in flight across barrier+MFMA ----
    int jn = (it < 71) ? it + 1 : 71;
    short8 bnext[4], gn[4]; float4 wqn;
    loadB(wBt2, wave, m16, quad, jn, bnext);
    gather4(xT, bbase, q, jn, cif2, cwf4, px, gn, wqn);
    // ---- LDS-only barrier: outstanding global loads NOT drained ----
    barrier_lgkm();
    // ---- fragments + MFMA: wave does 4 M-tiles x 4 N-tiles ----
    short8 af[4];
#pragma unroll
    for (int mt = 0; mt < 4; ++mt)
      af[mt] = *(const short8*)(At + buf * 2560 + (mt * 16 + m16) * 40 + quad * 8);
#pragma unroll
    for (int mt = 0; mt < 4; ++mt)
#pragma unroll
      for (int j = 0; j < 4; ++j)
        acc[mt][j] = __builtin_amdgcn_mfma_f32_16x16x32_bf16(af[mt], bcur[j],
                                                             acc[mt][j], 0, 0, 0);
    // rotate pipeline registers
#pragma unroll
    for (int i = 0; i < 4; ++i) g[i] = gn[i];
    wq = wqn;
#pragma unroll
    for (int j = 0; j < 4; ++j) bcur[j] = bnext[j];
  }
  __syncthreads();   // full drain before smem reuse

  // ---- epilogue: transpose via LDS for coalesced stores ----
  float* ep = (float*)smem;   // [128][65] floats = 33280 B
  for (int half = 0; half < 2; ++half) {
    if ((wave >> 1) == half) {
#pragma unroll
      for (int mt = 0; mt < 4; ++mt)
#pragma unroll
        for (int j = 0; j < 4; ++j)
#pragma unroll
          for (int r = 0; r < 4; ++r) {
            int o_loc = (wave & 1) * 64 + j * 16 + m16;
            int ppx = mt * 16 + quad * 4 + r;
            ep[o_loc * 65 + ppx] = acc[mt][j][r];
          }
    }
    __syncthreads();
#pragma unroll 4
    for (int t = 0; t < 32; ++t) {
      int idx = t * 256 + tid;
      int o = idx >> 6, ppx = idx & 63;
      out[(((size_t)((b << 8) + half * 128 + o)) << 12) + (h << 6) + ppx] =
          ep[o * 65 + ppx];
    }
    __syncthreads();
  }
}

extern "C" void kernel_launch(void* const* d_in, const int* in_sizes, int n_in,
                              void* d_out, int out_size, void* d_ws, size_t ws_size,
                              hipStream_t stream) {
  const float* x     = (const float*)d_in[0];
  const float* offw  = (const float*)d_in[1];
  const float* offb  = (const float*)d_in[2];
  const float* convw = (const float*)d_in[3];
  float* out = (float*)d_out;

  char* ws = (char*)d_ws;
  float* off_buf = (float*)ws;                               // 2,359,296 B
  float* part    = (float*)(ws + 2359296);                   // 18,874,368 B
  unsigned short* wBt2 = (unsigned short*)(ws + 21233664);   // 1,179,648 B
  unsigned short* xT   = (unsigned short*)(ws + 22413312);   // 16,777,216 B

  prep_xT<<<512, 256, 0, stream>>>(x, xT);
  prep_weights<<<2304, 256, 0, stream>>>(convw, wBt2);
  offset_partial<<<1024, 256, 0, stream>>>(x, offw, part);
  offset_reduce<<<2304, 256, 0, stream>>>(part, offb, off_buf);
  deform_main<<<512, 256, 0, stream>>>(xT, off_buf, wBt2, out);
}

// Round 5
// 190.432 us; speedup vs baseline: 3.6002x; 1.4081x over previous
//
#include <hip/hip_runtime.h>

using short8 = __attribute__((ext_vector_type(8))) short;
using f32x4  = __attribute__((ext_vector_type(4))) float;

__device__ inline unsigned short f2bf(float f) {
  unsigned u = __float_as_uint(f);
  u += 0x7fffu + ((u >> 16) & 1u);
  return (unsigned short)(u >> 16);
}
__device__ inline float bf2f(short s) {
  return __uint_as_float(((unsigned)(unsigned short)s) << 16);
}

// barrier that waits LDS only — global loads stay outstanding (pipeline!)
__device__ inline void barrier_lgkm() {
  asm volatile("s_waitcnt lgkmcnt(0)\n\ts_barrier" ::: "memory");
}

// ---------------- Kernel 0a: x NCHW fp32 -> xT[b][y*64+x][c] bf16 ----------------
__global__ __launch_bounds__(256) void prep_xT(const float* __restrict__ x,
                                               unsigned short* __restrict__ xT) {
  __shared__ unsigned short tile[64 * 260];   // [x][c], stride 260 (33280 B)
  int b = blockIdx.x >> 6, y = blockIdx.x & 63;
  int xc = threadIdx.x & 63, cq = threadIdx.x >> 6;
#pragma unroll 4
  for (int i = 0; i < 64; ++i) {
    int c = i * 4 + cq;
    float v = x[((size_t)((b << 8) + c) << 12) + (y << 6) + xc];
    tile[xc * 260 + c] = f2bf(v);
  }
  __syncthreads();
  int tid = threadIdx.x;
#pragma unroll 4
  for (int i = 0; i < 16; ++i) {
    int u = i * 256 + tid;            // 4096 units of 4 ch
    int site = u >> 6, c4 = u & 63;   // site = x (row y fixed)
    ushort4 val = *(const ushort4*)(tile + site * 260 + c4 * 4);
    *(ushort4*)(xT + ((size_t)((b << 12) + (y << 6) + site) << 8) + c4 * 4) = val;
  }
}

// ---------------- Kernel 0b: conv weights -> wBt2[ks][o(256)][kc(32)] bf16 ----------------
__global__ void prep_weights(const float* __restrict__ cw,
                             unsigned short* __restrict__ wBt2) {
  int e = blockIdx.x * 256 + threadIdx.x;   // < 589824
  int kc = e & 31, o = (e >> 5) & 255, ks = e >> 13;
  int c = (ks & 7) * 32 + kc, kt = ks >> 3;
  wBt2[e] = f2bf(cw[(size_t)(o * 256 + c) * 9 + kt]);
}

// ---------------- Kernel 0c: offset weights -> wOt[ks][o(32, pad0)][kc(32)] bf16 ----------------
__global__ void prep_offw(const float* __restrict__ ow,
                          unsigned short* __restrict__ wOt) {
  int e = blockIdx.x * 256 + threadIdx.x;   // < 73728
  int kc = e & 31, o = (e >> 5) & 31, ks = e >> 10;
  int c = (ks & 7) * 32 + kc, kt = ks >> 3;
  float v = (o < 18) ? ow[(size_t)(o * 256 + c) * 9 + kt] : 0.f;
  wOt[e] = f2bf(v);
}

// ---------------- offset-conv helpers ----------------
__device__ inline void gatherOff(const unsigned short* __restrict__ xT,
                                 int b, int h, int px, int q, int jt,
                                 short8& g, bool& val) {
  int cc = jt / 9, kt = jt - cc * 9;
  int ky = kt / 3, kx = kt - ky * 3;
  int y = h + ky - 1, xx = px + kx - 1;
  val = ((unsigned)y < 64u) && ((unsigned)xx < 64u);
  int yc = min(max(y, 0), 63), xc = min(max(xx, 0), 63);
  g = *(const short8*)(xT + (((size_t)((b << 12) + (yc << 6) + xc)) << 8) +
                       cc * 32 + q * 8);
}

__device__ inline void loadBOff(const unsigned short* __restrict__ wOt,
                                int m16, int quad, int jt, short8* bf) {
  int cc = jt / 9, kt = jt - cc * 9;
  int ks = kt * 8 + cc;
  const unsigned short* bp = wOt + (ks << 10) + m16 * 32 + quad * 8;
  bf[0] = *(const short8*)bp;
  bf[1] = *(const short8*)(bp + 512);
}

// ---------------- Kernel 1: offset conv via MFMA ----------------
// block = (b,h) row: M=64 px, N=32 (18 live), K=2304. Same verified MFMA
// conventions + lgkm-barrier pipeline as deform_main.
__global__ __launch_bounds__(256, 2) void offset_conv(
    const unsigned short* __restrict__ xT, const unsigned short* __restrict__ wOt,
    const float* __restrict__ offb, float* __restrict__ off_buf) {
  __shared__ unsigned short At[2 * 2560];   // 2 x [64][40]
  int tid = threadIdx.x, lane = tid & 63, wave = tid >> 6;
  int b = blockIdx.x & 7, h = blockIdx.x >> 3;
  int m16 = lane & 15, quad = lane >> 4;
  int px = wave * 16 + (lane >> 2), q = lane & 3;
  f32x4 acc[2];
  acc[0] = (f32x4){0.f, 0.f, 0.f, 0.f};
  acc[1] = acc[0];

  short8 g; bool val; short8 bcur[2];
  gatherOff(xT, b, h, px, q, 0, g, val);
  loadBOff(wOt, m16, quad, 0, bcur);

  for (int it = 0; it < 72; ++it) {
    int buf = it & 1;
    short8 av;
#pragma unroll
    for (int i = 0; i < 8; ++i) av[i] = val ? g[i] : (short)0;
    *(short8*)(At + buf * 2560 + px * 40 + q * 8) = av;
    int jn = (it < 71) ? it + 1 : 71;
    short8 gn; bool valn; short8 bnext[2];
    loadBOff(wOt, m16, quad, jn, bnext);
    gatherOff(xT, b, h, px, q, jn, gn, valn);
    barrier_lgkm();
    short8 af = *(const short8*)(At + buf * 2560 + (wave * 16 + m16) * 40 + quad * 8);
    acc[0] = __builtin_amdgcn_mfma_f32_16x16x32_bf16(af, bcur[0], acc[0], 0, 0, 0);
    acc[1] = __builtin_amdgcn_mfma_f32_16x16x32_bf16(af, bcur[1], acc[1], 0, 0, 0);
    g = gn; val = valn; bcur[0] = bnext[0]; bcur[1] = bnext[1];
  }
  // epilogue: D row = px (wave*16+quad*4+r), col = o (j*16+m16); add bias
#pragma unroll
  for (int j = 0; j < 2; ++j) {
    int o = j * 16 + m16;
    if (o < 18) {
      float bias = offb[o];
      float* dst = off_buf + (((size_t)(b * 18 + o)) << 12) + (h << 6) +
                   wave * 16 + quad * 4;
#pragma unroll
      for (int r = 0; r < 4; ++r) dst[r] = acc[j][r] + bias;
    }
  }
}

// ---------------- deform_main helpers ----------------
__device__ inline void gather4(const unsigned short* __restrict__ xT,
                               int bbase, int q, int jt,
                               const int2* cif2, const float4* cwf4,
                               int px, short8* g, float4& wq) {
  int cc = jt / 9, kt = jt - cc * 9;
  int2 si = cif2[kt * 64 + px];
  wq = cwf4[kt * 64 + px];
  const unsigned short* base = xT + (size_t)(unsigned)(bbase + cc * 32 + q * 8);
  g[0] = *(const short8*)(base + si.x);
  g[1] = *(const short8*)(base + si.x + 256);
  g[2] = *(const short8*)(base + si.y);
  g[3] = *(const short8*)(base + si.y + 256);
}

__device__ inline void loadB(const unsigned short* __restrict__ wBt2, int wave,
                             int m16, int quad, int jt, short8* bf) {
  int cc = jt / 9, kt = jt - cc * 9;
  int ks = kt * 8 + cc;
  const unsigned short* bp =
      wBt2 + ((size_t)ks << 13) + (wave << 11) + m16 * 32 + quad * 8;
#pragma unroll
  for (int j = 0; j < 4; ++j)
    bf[j] = *(const short8*)(bp + j * 512);
}

// ---------------- Kernel 2: fused sample + MFMA GEMM ----------------
__global__ __launch_bounds__(256, 2) void deform_main(
    const unsigned short* __restrict__ xT, const float* __restrict__ off,
    const unsigned short* __restrict__ wBt2, float* __restrict__ out) {
  __shared__ float4 smem4[2080];               // 33280 B
  char* smem = (char*)smem4;
  float4* cwf4 = (float4*)smem;                          // 576*16 = 9216 B
  int2*   cif2 = (int2*)(smem + 9216);                   // 576*8  = 4608 B
  unsigned short* At = (unsigned short*)(smem + 13824);  // 2 x [64][40] bf16

  int tid = threadIdx.x, lane = tid & 63, wave = tid >> 6;
  int b = blockIdx.x & 7, h = blockIdx.x >> 3;

  // --- coord/bilinear precompute (sites scaled by 256 = channel stride) ---
  for (int it = tid; it < 576; it += 256) {
    int k = it >> 6, px = it & 63;
    int ky = k / 3, kx = k - ky * 3;
    float dy = off[((size_t)(b * 18 + 2 * k) << 12) + (h << 6) + px];
    float dx = off[((size_t)(b * 18 + 2 * k + 1) << 12) + (h << 6) + px];
    float py = (float)(h - 1 + ky) + dy;
    float pxx = (float)(px - 1 + kx) + dx;
    float y0f = floorf(py), x0f = floorf(pxx);
    int y0 = (int)y0f, x0 = (int)x0f;
    float wy1 = py - y0f, wx1 = pxx - x0f;
    int xb; float wxl, wxr;
    if (x0 >= 0 && x0 <= 62)      { xb = x0; wxl = 1.f - wx1; wxr = wx1; }
    else if (x0 == -1)            { xb = 0;  wxl = wx1;       wxr = 0.f; }
    else if (x0 == 63)            { xb = 62; wxl = 0.f;       wxr = 1.f - wx1; }
    else                          { xb = 0;  wxl = 0.f;       wxr = 0.f; }
    float wy0v = ((unsigned)y0 < 64u) ? (1.f - wy1) : 0.f;
    float wy1v = ((unsigned)(y0 + 1) < 64u) ? wy1 : 0.f;
    int yc0 = min(max(y0, 0), 63), yc1 = min(max(y0 + 1, 0), 63);
    cwf4[it] = make_float4(wy0v * wxl, wy0v * wxr, wy1v * wxl, wy1v * wxr);
    cif2[it] = make_int2(((yc0 << 6) + xb) << 8, ((yc1 << 6) + xb) << 8);
  }
  __syncthreads();

  int m16 = lane & 15, quad = lane >> 4;
  int px = wave * 16 + (lane >> 2);   // gather mapping: quad <-> (px,corner) run
  int q  = lane & 3;                  // 8-ch slice within the 32-ch run
  int bbase = b << 20;
  f32x4 acc[4][4];
#pragma unroll
  for (int i = 0; i < 4; ++i)
#pragma unroll
    for (int j = 0; j < 4; ++j) acc[i][j] = (f32x4){0.f, 0.f, 0.f, 0.f};

  // prologue: prefetch iteration 0
  short8 g[4]; float4 wq; short8 bcur[4];
  gather4(xT, bbase, q, 0, cif2, cwf4, px, g, wq);
  loadB(wBt2, wave, m16, quad, 0, bcur);

  for (int it = 0; it < 72; ++it) {
    int buf = it & 1;
    // ---- bilinear combine + write A-tile (vmcnt waits on g use) ----
    short8 av;
#pragma unroll
    for (int i = 0; i < 8; ++i) {
      float v = wq.x * bf2f(g[0][i]) + wq.y * bf2f(g[1][i]) +
                wq.z * bf2f(g[2][i]) + wq.w * bf2f(g[3][i]);
      av[i] = (short)f2bf(v);
    }
    *(short8*)(At + buf * 2560 + px * 40 + q * 8) = av;
    // ---- prefetch it+1 — stays in flight across barrier+MFMA ----
    int jn = (it < 71) ? it + 1 : 71;
    short8 bnext[4], gn[4]; float4 wqn;
    loadB(wBt2, wave, m16, quad, jn, bnext);
    gather4(xT, bbase, q, jn, cif2, cwf4, px, gn, wqn);
    // ---- LDS-only barrier: outstanding global loads NOT drained ----
    barrier_lgkm();
    // ---- fragments + MFMA: wave does 4 M-tiles x 4 N-tiles ----
    short8 af[4];
#pragma unroll
    for (int mt = 0; mt < 4; ++mt)
      af[mt] = *(const short8*)(At + buf * 2560 + (mt * 16 + m16) * 40 + quad * 8);
#pragma unroll
    for (int mt = 0; mt < 4; ++mt)
#pragma unroll
      for (int j = 0; j < 4; ++j)
        acc[mt][j] = __builtin_amdgcn_mfma_f32_16x16x32_bf16(af[mt], bcur[j],
                                                             acc[mt][j], 0, 0, 0);
    // rotate pipeline registers
#pragma unroll
    for (int i = 0; i < 4; ++i) g[i] = gn[i];
    wq = wqn;
#pragma unroll
    for (int j = 0; j < 4; ++j) bcur[j] = bnext[j];
  }
  __syncthreads();   // full drain before smem reuse

  // ---- epilogue: transpose via LDS for coalesced stores ----
  float* ep = (float*)smem;   // [128][65] floats = 33280 B
  for (int half = 0; half < 2; ++half) {
    if ((wave >> 1) == half) {
#pragma unroll
      for (int mt = 0; mt < 4; ++mt)
#pragma unroll
        for (int j = 0; j < 4; ++j)
#pragma unroll
          for (int r = 0; r < 4; ++r) {
            int o_loc = (wave & 1) * 64 + j * 16 + m16;
            int ppx = mt * 16 + quad * 4 + r;
            ep[o_loc * 65 + ppx] = acc[mt][j][r];
          }
    }
    __syncthreads();
#pragma unroll 4
    for (int t = 0; t < 32; ++t) {
      int idx = t * 256 + tid;
      int o = idx >> 6, ppx = idx & 63;
      out[(((size_t)((b << 8) + half * 128 + o)) << 12) + (h << 6) + ppx] =
          ep[o * 65 + ppx];
    }
    __syncthreads();
  }
}

extern "C" void kernel_launch(void* const* d_in, const int* in_sizes, int n_in,
                              void* d_out, int out_size, void* d_ws, size_t ws_size,
                              hipStream_t stream) {
  const float* x     = (const float*)d_in[0];
  const float* offw  = (const float*)d_in[1];
  const float* offb  = (const float*)d_in[2];
  const float* convw = (const float*)d_in[3];
  float* out = (float*)d_out;

  char* ws = (char*)d_ws;
  float* off_buf = (float*)ws;                              // 2,359,296 B
  unsigned short* wOt  = (unsigned short*)(ws + 2359296);   //   147,456 B
  unsigned short* wBt2 = (unsigned short*)(ws + 2506752);   // 1,179,648 B
  unsigned short* xT   = (unsigned short*)(ws + 3686400);   // 16,777,216 B

  prep_xT<<<512, 256, 0, stream>>>(x, xT);
  prep_weights<<<2304, 256, 0, stream>>>(convw, wBt2);
  prep_offw<<<288, 256, 0, stream>>>(offw, wOt);
  offset_conv<<<512, 256, 0, stream>>>(xT, wOt, offb, off_buf);
  deform_main<<<512, 256, 0, stream>>>(xT, off_buf, wBt2, out);
}